// Round 5
// baseline (40413.129 us; speedup 1.0000x reference)
//
#include <hip/hip_runtime.h>
#include <hip/hip_bf16.h>
#include <math.h>

#define IDIM 128
#define HDIM 512
#define SDIM 64
#define BATCH 128
#define MAXT 259
#define G4 2048
#define KTOT 704   // 128 (x) + 64 (rt) + 512 (h)
#define ROUT 194   // 64 + 128 + 2

typedef __hip_bfloat16 bf16;
typedef __attribute__((ext_vector_type(8))) short short8;
typedef __attribute__((ext_vector_type(4))) float floatx4;

__device__ __forceinline__ float sigmoidf_(float v) { return 1.f / (1.f + expf(-v)); }
__device__ __forceinline__ float b2f(bf16 v) { return __bfloat162float(v); }
__device__ __forceinline__ float load_in(const void* p, size_t i, int isf32) {
    return isf32 ? ((const float*)p)[i] : b2f(((const bf16*)p)[i]);
}
__device__ __forceinline__ unsigned short f2bfbits(float v) {
    unsigned u = __builtin_bit_cast(unsigned, v);
    unsigned r = (u + 0x7FFFu + ((u >> 16) & 1u)) >> 16;
    return (unsigned short)r;
}
__device__ __forceinline__ float bfbits2f(unsigned short b) {
    return __builtin_bit_cast(float, (unsigned)b << 16);
}

// dtype detect (defensive): f32 data has random low halves -> bf16-exp >= 0x8F
__global__ void detect_kernel(const unsigned short* __restrict__ w, int* __restrict__ flag) {
    if (threadIdx.x == 0) {
        int isf32 = 0;
        for (int i = 0; i < 256; i++) {
            int e = (w[i] >> 7) & 0xFF;
            if (e >= 0x8F) isf32 = 1;
        }
        *flag = isf32;
    }
}

// Gate-interleaved combined weights in B-fragment layout (hi/lo bf16 split).
// j' = 4u+gate <- source row gate*512+u of [Wih|Whh].
// WfH[((jt*22 + ks)*64 + q*16 + jn)*8 + e], jt=j'/16, jn=j'%16, ks=k/32, q=(k%32)/8, e=k%8.
__global__ void prep_kernel(const void* __restrict__ Wih, const void* __restrict__ bih,
                            const void* __restrict__ Whh, const void* __restrict__ bhh,
                            unsigned short* __restrict__ WfH, unsigned short* __restrict__ WfL,
                            float* __restrict__ bc, const int* __restrict__ flag) {
    int isf32 = *flag;
    int jp = blockIdx.x;              // 0..2047
    int u = jp >> 2, gate = jp & 3;
    int src = gate * HDIM + u;
    int jt = jp >> 4, jn = jp & 15;
    for (int k = threadIdx.x; k < KTOT; k += blockDim.x) {
        float v = (k < 192) ? load_in(Wih, (size_t)src * 192 + k, isf32)
                            : load_in(Whh, (size_t)src * HDIM + (k - 192), isf32);
        unsigned short hi = f2bfbits(v);
        unsigned short lo = f2bfbits(v - bfbits2f(hi));   // 0 if v already bf16
        int ks = k >> 5, q = (k & 31) >> 3, e = k & 7;
        size_t d = (((size_t)jt * 22 + ks) * 64 + (q * 16 + jn)) * 8 + e;
        WfH[d] = hi;
        WfL[d] = lo;
    }
    if (threadIdx.x == 0)
        bc[jp] = load_in(bih, src, isf32) + load_in(bhh, src, isf32);
}

// Wr (194x512, padded to 208) -> B-fragment layout, K=512 (16 ks).
__global__ void wr_prep_kernel(const void* __restrict__ Wr, const void* __restrict__ br,
                               unsigned short* __restrict__ WrF, unsigned short* __restrict__ WrL,
                               float* __restrict__ brf, const int* __restrict__ flag) {
    int isf32 = *flag;
    int j = blockIdx.x;               // 0..207
    int jt = j >> 4, jn = j & 15;
    for (int k = threadIdx.x; k < HDIM; k += blockDim.x) {
        float v = (j < ROUT) ? load_in(Wr, (size_t)j * HDIM + k, isf32) : 0.f;
        unsigned short hi = f2bfbits(v);
        unsigned short lo = f2bfbits(v - bfbits2f(hi));
        int ks = k >> 5, q = (k & 31) >> 3, e = k & 7;
        size_t d = (((size_t)jt * 16 + ks) * 64 + (q * 16 + jn)) * 8 + e;
        WrF[d] = hi;
        WrL[d] = lo;
    }
    if (threadIdx.x == 0) brf[j] = (j < ROUT) ? load_in(br, j, isf32) : 0.f;
}

// ---------------- persistent monolith ----------------
// 8 blocks x 1024 threads. Block bi owns batch rows bi*16..bi*16+15 and runs
// the whole 259-step recurrence. No inter-block communication exists.
__global__ __launch_bounds__(1024) void mono_kernel(
        const void* __restrict__ x,
        const unsigned short* __restrict__ WfH, const unsigned short* __restrict__ WfL,
        const float* __restrict__ bc,
        const unsigned short* __restrict__ WrF, const unsigned short* __restrict__ WrL,
        const float* __restrict__ brf,
        float* __restrict__ V, void* __restrict__ dout,
        const int* __restrict__ flag) {
    __shared__ __align__(16) short Ah[22 * 64 * 8];     // A-frags hi (x|rt|h)
    __shared__ __align__(16) short Al[22 * 64 * 8];     // A-frags lo
    __shared__ __align__(16) float hfull[16][520];      // h state f32
    __shared__ __align__(16) float sS[16][264];         // stack strengths
    __shared__ __align__(16) float aS[16][264];         // A coefficients
    __shared__ __align__(16) float rtS[16][64];         // stack read vector
    __shared__ __align__(16) float outS[16][212];       // readout row
    __shared__ __align__(16) float scr[16][16][20];     // per-wave C-tile roundtrip
    __shared__ __align__(16) float bcS[2048];
    __shared__ __align__(16) float brS[208];

    const int tid = threadIdx.x;
    const int lane = tid & 63, wv = tid >> 6;
    const int b0 = blockIdx.x * 16;
    const int isf32 = *flag;

    // ---- init: zero frags/s/rt, load biases ----
    for (int i = tid; i < 22 * 64 * 8; i += 1024) { Ah[i] = 0; Al[i] = 0; }
    for (int i = tid; i < 16 * 264; i += 1024) ((float*)sS)[i] = 0.f;
    for (int i = tid; i < 16 * 64; i += 1024) ((float*)rtS)[i] = 0.f;
    for (int i = tid; i < 2048; i += 1024) bcS[i] = bc[i];
    if (tid < 208) brS[tid] = brf[tid];
    __syncthreads();

    float cc[8];
    #pragma unroll
    for (int i = 0; i < 8; i++) cc[i] = 0.f;

    const short8* AhF = (const short8*)Ah;
    const short8* AlF = (const short8*)Al;
    const short8* WH = (const short8*)WfH;
    const short8* WL = (const short8*)WfL;
    const short8* WrH = (const short8*)WrF;
    const short8* WrLo = (const short8*)WrL;

    for (int t = 0; t < MAXT; t++) {
        const int use_x = (t < 129);

        // ---- P0: stage x (ks 0..3) and rt (ks 4..5) into A-frags ----
        if (tid < 384) {
            int ks = tid >> 6, l = tid & 63;
            int q = l >> 4, m = l & 15;
            int k0 = ks * 32 + q * 8;
            int fi = (ks * 64 + l) * 8;
            if (ks < 4) {
                if (use_x) {
                    size_t xi = ((size_t)t * BATCH + b0 + m) * IDIM + k0;
                    if (isf32) {
                        const float* xf = (const float*)x + xi;
                        short8 hi, lo;
                        #pragma unroll
                        for (int i = 0; i < 8; i++) {
                            unsigned short hb = f2bfbits(xf[i]);
                            hi[i] = (short)hb;
                            lo[i] = (short)f2bfbits(xf[i] - bfbits2f(hb));
                        }
                        *(short8*)&Ah[fi] = hi;
                        *(short8*)&Al[fi] = lo;
                    } else {
                        *(short8*)&Ah[fi] = *(const short8*)((const unsigned short*)x + xi);
                    }
                }
            } else {
                int kr = k0 - 128;                    // 0..56
                short8 hi, lo;
                #pragma unroll
                for (int i = 0; i < 8; i++) {
                    float v = rtS[m][kr + i];
                    unsigned short hb = f2bfbits(v);
                    hi[i] = (short)hb;
                    lo[i] = (short)f2bfbits(v - bfbits2f(hb));
                }
                *(short8*)&Ah[fi] = hi;
                *(short8*)&Al[fi] = lo;
            }
        }
        __syncthreads();

        // ---- P1: gates MFMA. wave wv owns N-tiles wv+16i ----
        floatx4 acc[8];
        #pragma unroll
        for (int i = 0; i < 8; i++) acc[i] = (floatx4){0.f, 0.f, 0.f, 0.f};
        for (int ks = use_x ? 0 : 4; ks < 22; ks++) {
            short8 ah = AhF[ks * 64 + lane];
            const int lo_on = (ks >= 4) || (isf32 && use_x);
            short8 al;
            if (lo_on) al = AlF[ks * 64 + lane];
            #pragma unroll
            for (int i = 0; i < 8; i++) {
                int nt = wv + 16 * i;
                short8 bh = WH[(nt * 22 + ks) * 64 + lane];
                acc[i] = __builtin_amdgcn_mfma_f32_16x16x32_bf16(ah, bh, acc[i], 0, 0, 0);
                if (lo_on)
                    acc[i] = __builtin_amdgcn_mfma_f32_16x16x32_bf16(al, bh, acc[i], 0, 0, 0);
                if (isf32) {
                    short8 bl = WL[(nt * 22 + ks) * 64 + lane];
                    acc[i] = __builtin_amdgcn_mfma_f32_16x16x32_bf16(ah, bl, acc[i], 0, 0, 0);
                }
            }
        }

        // ---- P2: cell epilogue (per-wave scr roundtrip; c in regs; h -> hfull) ----
        {
            int n = lane & 15, m0 = (lane >> 4) * 4;
            int mp = lane >> 2, ul = lane & 3;
            #pragma unroll
            for (int i = 0; i < 8; i++) {
                int nt = wv + 16 * i;
                *(floatx4*)&scr[wv][n][m0] = acc[i];
                int jb = nt * 16 + ul * 4;
                float g0 = scr[wv][ul * 4 + 0][mp] + bcS[jb + 0];
                float g1 = scr[wv][ul * 4 + 1][mp] + bcS[jb + 1];
                float g2 = scr[wv][ul * 4 + 2][mp] + bcS[jb + 2];
                float g3 = scr[wv][ul * 4 + 3][mp] + bcS[jb + 3];
                float c2 = sigmoidf_(g1) * cc[i] + sigmoidf_(g0) * tanhf(g2);
                float h2 = sigmoidf_(g3) * tanhf(c2);
                cc[i] = c2;
                hfull[mp][nt * 4 + ul] = h2;
            }
        }
        __syncthreads();

        // ---- P2.5: restage h -> A-frags ks 6..21 (1 slot/thread) ----
        {
            int ks = 6 + (tid >> 6), l = tid & 63;
            int q = l >> 4, m = l & 15;
            int k0 = (ks - 6) * 32 + q * 8;
            short8 hi, lo;
            #pragma unroll
            for (int i = 0; i < 8; i++) {
                float v = hfull[m][k0 + i];
                unsigned short hb = f2bfbits(v);
                hi[i] = (short)hb;
                lo[i] = (short)f2bfbits(v - bfbits2f(hb));
            }
            int fi = (ks * 64 + l) * 8;
            *(short8*)&Ah[fi] = hi;
            *(short8*)&Al[fi] = lo;
        }
        __syncthreads();

        // ---- P3: readout MFMA (waves 0..12, tile jt = wv) ----
        if (wv < 13) {
            floatx4 r = {0.f, 0.f, 0.f, 0.f};
            for (int ks = 0; ks < 16; ks++) {
                short8 ah = AhF[(6 + ks) * 64 + lane];
                short8 al = AlF[(6 + ks) * 64 + lane];
                short8 bh = WrH[(wv * 16 + ks) * 64 + lane];
                r = __builtin_amdgcn_mfma_f32_16x16x32_bf16(ah, bh, r, 0, 0, 0);
                r = __builtin_amdgcn_mfma_f32_16x16x32_bf16(al, bh, r, 0, 0, 0);
                if (isf32) {
                    short8 bl = WrLo[(wv * 16 + ks) * 64 + lane];
                    r = __builtin_amdgcn_mfma_f32_16x16x32_bf16(ah, bl, r, 0, 0, 0);
                }
            }
            *(floatx4*)&scr[wv][lane & 15][(lane >> 4) * 4] = r;
            int mp = lane & 15, n4 = (lane >> 4) * 4;
            int j = wv * 16 + n4;
            float4 bb = *(const float4*)&brS[j];
            float4 ov;
            ov.x = scr[wv][n4 + 0][mp] + bb.x;
            ov.y = scr[wv][n4 + 1][mp] + bb.y;
            ov.z = scr[wv][n4 + 2][mp] + bb.z;
            ov.w = scr[wv][n4 + 3][mp] + bb.w;
            *(float4*)&outS[mp][j] = ov;
        }
        __syncthreads();

        // ---- P4: stack update + rt + output (wave wv = batch row wv) ----
        {
            float uval = sigmoidf_(outS[wv][192]);
            float dval = sigmoidf_(outS[wv][193]);
            float vt = outS[wv][lane];
            size_t vrowbase = ((size_t)(b0 + wv) * MAXT) * SDIM;
            V[vrowbase + (size_t)t * SDIM + lane] = vt;

            // suffix scan of s_old: 5 elems/lane
            int ebase = lane * 5;
            float sv[5], suf[5];
            #pragma unroll
            for (int j = 0; j < 5; j++) {
                int e = ebase + j;
                sv[j] = (e < MAXT) ? sS[wv][e] : 0.f;
            }
            suf[4] = sv[4];
            #pragma unroll
            for (int j = 3; j >= 0; j--) suf[j] = sv[j] + suf[j + 1];
            float ltot = suf[0];
            float accs = ltot;
            #pragma unroll
            for (int off = 1; off < 64; off <<= 1) {
                float y = __shfl_down(accs, off, 64);
                if (lane + off < 64) accs += y;
            }
            float after_lane = accs - ltot;     // sum over lanes > lane
            #pragma unroll
            for (int j = 0; j < 5; j++) {
                int e = ebase + j;
                if (e < MAXT) {
                    float prod = after_lane + (suf[j] - sv[j]);
                    float sp = (e == t) ? dval
                                        : fmaxf(0.f, sv[j] - fmaxf(0.f, uval - prod));
                    float inner = fmaxf(0.f, 1.f - prod - sp);
                    sS[wv][e] = sp;
                    aS[wv][e] = fminf(sp, inner);
                }
            }
            // rt = sum_{i<=t} A[i] * V[b][i][:]
            float racc = aS[wv][t] * vt;
            const float* vrow = V + vrowbase + lane;
            for (int i = 0; i < t; i++)
                racc += aS[wv][i] * vrow[(size_t)i * SDIM];
            rtS[wv][lane] = racc;

            if (t >= 129) {
                float a = outS[wv][64 + lane];
                float bvv = outS[wv][128 + lane];
                float m = fmaxf(a, bvv);
                #pragma unroll
                for (int off = 32; off; off >>= 1) m = fmaxf(m, __shfl_xor(m, off, 64));
                float e = expf(a - m) + expf(bvv - m);
                #pragma unroll
                for (int off = 32; off; off >>= 1) e += __shfl_xor(e, off, 64);
                float ls = logf(e) + m;
                size_t base = ((size_t)(t - 129) * BATCH + b0 + wv) * IDIM;
                if (isf32) {
                    ((float*)dout)[base + lane] = a - ls;
                    ((float*)dout)[base + lane + 64] = bvv - ls;
                } else {
                    ((bf16*)dout)[base + lane] = __float2bfloat16(a - ls);
                    ((bf16*)dout)[base + lane + 64] = __float2bfloat16(bvv - ls);
                }
            }
        }
        __syncthreads();
    }
}

extern "C" void kernel_launch(void* const* d_in, const int* in_sizes, int n_in,
                              void* d_out, int out_size, void* d_ws, size_t ws_size,
                              hipStream_t stream) {
    const void* x   = d_in[0];
    const void* Wih = d_in[1];
    const void* bih = d_in[2];
    const void* Whh = d_in[3];
    const void* bhh = d_in[4];
    const void* Wr  = d_in[5];
    const void* br  = d_in[6];

    char* base = (char*)d_ws;
    int* flag = (int*)base;                                      size_t off = 64;
    unsigned short* WfH = (unsigned short*)(base + off);         off += (size_t)G4 * KTOT * 2;
    unsigned short* WfL = (unsigned short*)(base + off);         off += (size_t)G4 * KTOT * 2;
    unsigned short* WrF = (unsigned short*)(base + off);         off += (size_t)208 * HDIM * 2;
    unsigned short* WrL = (unsigned short*)(base + off);         off += (size_t)208 * HDIM * 2;
    float* bc  = (float*)(base + off);                           off += G4 * 4;
    float* brf = (float*)(base + off);                           off += 208 * 4;
    float* V   = (float*)(base + off);                           // 128*259*64 f32

    detect_kernel<<<1, 64, 0, stream>>>((const unsigned short*)Wih, flag);
    prep_kernel<<<G4, 256, 0, stream>>>(Wih, bih, Whh, bhh, WfH, WfL, bc, flag);
    wr_prep_kernel<<<208, 256, 0, stream>>>(Wr, br, WrF, WrL, brf, flag);

    mono_kernel<<<8, 1024, 0, stream>>>(x, WfH, WfL, bc, WrF, WrL, brf, V, d_out, flag);

    (void)in_sizes; (void)n_in; (void)out_size; (void)ws_size;
}

// Round 7
// 19280.951 us; speedup vs baseline: 2.0960x; 2.0960x over previous
//
#include <hip/hip_runtime.h>
#include <hip/hip_bf16.h>
#include <math.h>

#define IDIM 128
#define HDIM 512
#define SDIM 64
#define BATCH 128
#define MAXT 259
#define G4 2048
#define KTOT 704   // 128 (x) + 64 (rt) + 512 (h)
#define ROUT 194   // 64 + 128 + 2
#define AFRAG_SH 73728   // 8 mt * 18 ks * 64 lanes * 8 e (shorts) per buffer
#define NBLK 128

typedef __hip_bfloat16 bf16;
typedef __attribute__((ext_vector_type(8))) short short8;
typedef __attribute__((ext_vector_type(4))) float floatx4;

__device__ __forceinline__ float sigmoidf_(float v) { return 1.f / (1.f + expf(-v)); }
__device__ __forceinline__ float b2f(bf16 v) { return __bfloat162float(v); }
__device__ __forceinline__ float load_in(const void* p, size_t i, int isf32) {
    return isf32 ? ((const float*)p)[i] : b2f(((const bf16*)p)[i]);
}
__device__ __forceinline__ unsigned short f2bfbits(float v) {
    unsigned u = __builtin_bit_cast(unsigned, v);
    unsigned r = (u + 0x7FFFu + ((u >> 16) & 1u)) >> 16;
    return (unsigned short)r;
}
__device__ __forceinline__ float bfbits2f(unsigned short b) {
    return __builtin_bit_cast(float, (unsigned)b << 16);
}

// Software grid barrier: 128 co-resident blocks (<=256 CUs guarantees residency).
// Sense-reversing; device-scope atomics give cross-XCD release/acquire.
__device__ __forceinline__ void grid_barrier(unsigned* cnt, unsigned* gen) {
    __syncthreads();
    if (threadIdx.x == 0) {
        unsigned g = __hip_atomic_load(gen, __ATOMIC_RELAXED, __HIP_MEMORY_SCOPE_AGENT);
        __threadfence();   // release: publish this block's prior stores
        unsigned prev = __hip_atomic_fetch_add(cnt, 1u, __ATOMIC_ACQ_REL,
                                               __HIP_MEMORY_SCOPE_AGENT);
        if (prev == NBLK - 1) {
            __hip_atomic_store(cnt, 0u, __ATOMIC_RELAXED, __HIP_MEMORY_SCOPE_AGENT);
            __threadfence();
            __hip_atomic_store(gen, g + 1u, __ATOMIC_RELEASE, __HIP_MEMORY_SCOPE_AGENT);
        } else {
            while (__hip_atomic_load(gen, __ATOMIC_ACQUIRE,
                                     __HIP_MEMORY_SCOPE_AGENT) == g) {}
        }
        __threadfence();   // acquire: invalidate stale caches before post-barrier reads
    }
    __syncthreads();
}

// dtype detect (defensive): f32 data has random low halves -> bf16-exp >= 0x8F
__global__ void detect_kernel(const unsigned short* __restrict__ w, int* __restrict__ flag) {
    if (threadIdx.x == 0) {
        int isf32 = 0;
        for (int i = 0; i < 256; i++) {
            int e = (w[i] >> 7) & 0xFF;
            if (e >= 0x8F) isf32 = 1;
        }
        *flag = isf32;
    }
}

// Gate-interleaved combined weights in B-fragment layout (hi/lo bf16 split).
// j' = 4u+gate <- source row gate*512+u of [Wih|Whh].
// WfH[((jt*22 + ks)*64 + q*16 + jn)*8 + e], jt=j'/16, jn=j'%16, ks=k/32, q=(k%32)/8, e=k%8.
__global__ void prep_kernel(const void* __restrict__ Wih, const void* __restrict__ bih,
                            const void* __restrict__ Whh, const void* __restrict__ bhh,
                            unsigned short* __restrict__ WfH, unsigned short* __restrict__ WfL,
                            float* __restrict__ bc, const int* __restrict__ flag) {
    int isf32 = *flag;
    int jp = blockIdx.x;              // 0..2047
    int u = jp >> 2, gate = jp & 3;
    int src = gate * HDIM + u;
    int jt = jp >> 4, jn = jp & 15;
    for (int k = threadIdx.x; k < KTOT; k += blockDim.x) {
        float v = (k < 192) ? load_in(Wih, (size_t)src * 192 + k, isf32)
                            : load_in(Whh, (size_t)src * HDIM + (k - 192), isf32);
        unsigned short hi = f2bfbits(v);
        unsigned short lo = f2bfbits(v - bfbits2f(hi));   // 0 if v already bf16
        int ks = k >> 5, q = (k & 31) >> 3, e = k & 7;
        size_t d = (((size_t)jt * 22 + ks) * 64 + (q * 16 + jn)) * 8 + e;
        WfH[d] = hi;
        WfL[d] = lo;
    }
    if (threadIdx.x == 0)
        bc[jp] = load_in(bih, src, isf32) + load_in(bhh, src, isf32);
}

// Wr -> row-major bf16 hi/lo (208 rows, rows >=194 zero) + brf f32 (padded).
__global__ void wr_prep_kernel(const void* __restrict__ Wr, const void* __restrict__ br,
                               unsigned short* __restrict__ WrBh, unsigned short* __restrict__ WrBl,
                               float* __restrict__ brf, const int* __restrict__ flag) {
    int isf32 = *flag;
    int j = blockIdx.x;               // 0..207
    for (int k = threadIdx.x; k < HDIM; k += blockDim.x) {
        float v = (j < ROUT) ? load_in(Wr, (size_t)j * HDIM + k, isf32) : 0.f;
        unsigned short hi = f2bfbits(v);
        WrBh[(size_t)j * HDIM + k] = hi;
        WrBl[(size_t)j * HDIM + k] = f2bfbits(v - bfbits2f(hi));
    }
    if (threadIdx.x == 0) brf[j] = (j < ROUT) ? load_in(br, j, isf32) : 0.f;
}

// Pre-convert x[t] (t=0..128) into A-fragment layout (hi only; x-lo dropped
// even in f32 path — sub-threshold error).
// xF[t*16384 + ((mt*4+ks)*64 + q*16 + (m&15))*8 + e]
__global__ void x_prep_kernel(const void* __restrict__ x, unsigned short* __restrict__ xF,
                              const int* __restrict__ flag) {
    int isf32 = *flag;
    int t = blockIdx.x;               // 0..128
    for (int idx = threadIdx.x; idx < BATCH * IDIM; idx += blockDim.x) {
        int m = idx >> 7, k = idx & 127;
        float v = load_in(x, (size_t)t * BATCH * IDIM + idx, isf32);
        int mt = m >> 4, ks = k >> 5, q = (k & 31) >> 3, e = k & 7;
        size_t d = (size_t)t * 16384 + (((mt * 4 + ks) * 64) + q * 16 + (m & 15)) * 8 + e;
        xF[d] = f2bfbits(v);
    }
}

// ---------------- persistent kernel (software grid barrier) ----------------
// 128 blocks x 256 threads. blk = ms*32 + ns: gates stripe rows 32ms..+31,
// cols 64ns..+63. Stack/readout: block handles batch row b = blk.
__global__ __launch_bounds__(256) void persist_kernel(
        const unsigned short* __restrict__ xF,
        const unsigned short* __restrict__ WfH, const unsigned short* __restrict__ WfL,
        const float* __restrict__ bc,
        const unsigned short* __restrict__ WrBh, const unsigned short* __restrict__ WrBl,
        const float* __restrict__ brf,
        unsigned short* __restrict__ AfH, unsigned short* __restrict__ AfL,
        float* __restrict__ hG, unsigned short* __restrict__ Vb,
        void* __restrict__ dout, const int* __restrict__ flag,
        unsigned* __restrict__ bar) {
    __shared__ __align__(16) float scr[4][32][20];
    __shared__ __align__(16) float hs[HDIM];
    __shared__ __align__(16) float outs[208];
    __shared__ __align__(16) float sL[324];
    __shared__ __align__(16) float aL[324];
    __shared__ __align__(16) float red[4][64];
    __shared__ __align__(16) float blBc[64];
    __shared__ __align__(16) float brS[208];

    const int tid = threadIdx.x, lane = tid & 63, wv = tid >> 6;
    const int blk = blockIdx.x, ms = blk >> 5, ns = blk & 31;
    const int brow = blk;
    const int isf32 = *flag;
    unsigned* cnt = bar;
    unsigned* gen = bar + 16;   // separate cacheline-ish offset

    if (tid < 64) blBc[tid] = bc[ns * 64 + tid];
    for (int i = tid; i < 208; i += 256) brS[i] = brf[i];
    for (int i = tid; i < 324; i += 256) { sL[i] = 0.f; aL[i] = 0.f; }
    float cc0 = 0.f, cc1 = 0.f;
    __syncthreads();

    const short8* WH = (const short8*)WfH;
    const short8* WL = (const short8*)WfL;
    const int nt = ns * 4 + wv;
    unsigned short* Vrow = Vb + (size_t)brow * MAXT * SDIM;

    for (int t = 0; t < MAXT; t++) {
        const int cur = t & 1, nxt = cur ^ 1;
        const short8* AhC = (const short8*)(AfH + (size_t)cur * AFRAG_SH);
        const short8* AlC = (const short8*)(AfL + (size_t)cur * AFRAG_SH);
        unsigned short* AfHn = AfH + (size_t)nxt * AFRAG_SH;
        unsigned short* AfLn = AfL + (size_t)nxt * AFRAG_SH;
        const int use_x = (t < 129);

        // ---- P1: gates MFMA (wave: 2 M-tiles x 1 N-tile) ----
        floatx4 acc0 = {0.f, 0.f, 0.f, 0.f}, acc1 = {0.f, 0.f, 0.f, 0.f};
        const short8* wb = WH + (size_t)nt * 22 * 64;
        const short8* wbl = WL + (size_t)nt * 22 * 64;
        if (use_x) {
            const short8* xb = (const short8*)xF + (size_t)t * 2048;
            #pragma unroll
            for (int ks = 0; ks < 4; ks++) {
                short8 bh = wb[ks * 64 + lane];
                short8 a0 = xb[((2 * ms + 0) * 4 + ks) * 64 + lane];
                short8 a1 = xb[((2 * ms + 1) * 4 + ks) * 64 + lane];
                acc0 = __builtin_amdgcn_mfma_f32_16x16x32_bf16(a0, bh, acc0, 0, 0, 0);
                acc1 = __builtin_amdgcn_mfma_f32_16x16x32_bf16(a1, bh, acc1, 0, 0, 0);
                if (isf32) {
                    short8 bl = wbl[ks * 64 + lane];
                    acc0 = __builtin_amdgcn_mfma_f32_16x16x32_bf16(a0, bl, acc0, 0, 0, 0);
                    acc1 = __builtin_amdgcn_mfma_f32_16x16x32_bf16(a1, bl, acc1, 0, 0, 0);
                }
            }
        }
        for (int ksi = 0; ksi < 18; ksi++) {
            int ks = ksi + 4;
            short8 bh = wb[ks * 64 + lane];
            short8 a0h = AhC[((2 * ms + 0) * 18 + ksi) * 64 + lane];
            short8 a0l = AlC[((2 * ms + 0) * 18 + ksi) * 64 + lane];
            short8 a1h = AhC[((2 * ms + 1) * 18 + ksi) * 64 + lane];
            short8 a1l = AlC[((2 * ms + 1) * 18 + ksi) * 64 + lane];
            acc0 = __builtin_amdgcn_mfma_f32_16x16x32_bf16(a0h, bh, acc0, 0, 0, 0);
            acc0 = __builtin_amdgcn_mfma_f32_16x16x32_bf16(a0l, bh, acc0, 0, 0, 0);
            acc1 = __builtin_amdgcn_mfma_f32_16x16x32_bf16(a1h, bh, acc1, 0, 0, 0);
            acc1 = __builtin_amdgcn_mfma_f32_16x16x32_bf16(a1l, bh, acc1, 0, 0, 0);
            if (isf32) {
                short8 bl = wbl[ks * 64 + lane];
                acc0 = __builtin_amdgcn_mfma_f32_16x16x32_bf16(a0h, bl, acc0, 0, 0, 0);
                acc1 = __builtin_amdgcn_mfma_f32_16x16x32_bf16(a1h, bl, acc1, 0, 0, 0);
            }
        }
        // C layout: m = (lane>>4)*4 + reg, n = lane&15
        {
            int n = lane & 15, m0 = (lane >> 4) * 4;
            #pragma unroll
            for (int r = 0; r < 4; r++) scr[wv][m0 + r][n] = acc0[r];
            #pragma unroll
            for (int r = 0; r < 4; r++) scr[wv][16 + m0 + r][n] = acc1[r];
        }
        __syncthreads();
        // cell: thread -> (r = tid>>3, ul = tid&7 and +8)
        {
            int r = tid >> 3, ulb = tid & 7;
            #pragma unroll
            for (int i = 0; i < 2; i++) {
                int ul = ulb + 8 * i;
                float4 g = *(const float4*)&scr[ul >> 2][r][(ul & 3) * 4];
                float4 bb = *(const float4*)&blBc[ul * 4];
                float gi = g.x + bb.x, gf = g.y + bb.y, gg = g.z + bb.z, go = g.w + bb.w;
                float ccv = i ? cc1 : cc0;
                float c2 = sigmoidf_(gf) * ccv + sigmoidf_(gi) * tanhf(gg);
                float h2 = sigmoidf_(go) * tanhf(c2);
                if (i) cc1 = c2; else cc0 = c2;
                int m_g = ms * 32 + r, u_g = ns * 16 + ul;
                hG[m_g * HDIM + u_g] = h2;
                unsigned short hb = f2bfbits(h2);
                unsigned short lb = f2bfbits(h2 - bfbits2f(hb));
                int mt = m_g >> 4, ksi2 = 2 + (u_g >> 5), q = (u_g & 31) >> 3, e = u_g & 7;
                size_t fi = (((size_t)mt * 18 + ksi2) * 64 + q * 16 + (m_g & 15)) * 8 + e;
                AfHn[fi] = hb;
                AfLn[fi] = lb;
            }
        }
        grid_barrier(cnt, gen);

        // ---- P2: readout (VALU dot) + stack for batch row brow ----
        hs[tid] = hG[brow * HDIM + tid];
        hs[tid + 256] = hG[brow * HDIM + tid + 256];
        __syncthreads();
        for (int j = wv; j < ROUT; j += 4) {
            const short8 w8 = *(const short8*)(WrBh + (size_t)j * HDIM + lane * 8);
            const float* hp = &hs[lane * 8];
            float p = 0.f;
            #pragma unroll
            for (int i2 = 0; i2 < 8; i2++) p += bfbits2f((unsigned short)w8[i2]) * hp[i2];
            if (isf32) {
                const short8 wl8 = *(const short8*)(WrBl + (size_t)j * HDIM + lane * 8);
                #pragma unroll
                for (int i2 = 0; i2 < 8; i2++) p += bfbits2f((unsigned short)wl8[i2]) * hp[i2];
            }
            #pragma unroll
            for (int off = 32; off; off >>= 1) p += __shfl_down(p, off, 64);
            if (lane == 0) outs[j] = p + brS[j];
        }
        __syncthreads();

        if (wv == 0) {
            float uval = sigmoidf_(outs[192]);
            float dval = sigmoidf_(outs[193]);
            Vrow[(size_t)t * SDIM + lane] = f2bfbits(outs[lane]);
            // suffix scan, 5 elems/lane (verified in R5 mono)
            int ebase = lane * 5;
            float sv[5], suf[5];
            #pragma unroll
            for (int j = 0; j < 5; j++) {
                int e = ebase + j;
                sv[j] = (e < MAXT) ? sL[e] : 0.f;
            }
            suf[4] = sv[4];
            #pragma unroll
            for (int j = 3; j >= 0; j--) suf[j] = sv[j] + suf[j + 1];
            float ltot = suf[0];
            float accs = ltot;
            #pragma unroll
            for (int off = 1; off < 64; off <<= 1) {
                float y = __shfl_down(accs, off, 64);
                if (lane + off < 64) accs += y;
            }
            float after_lane = accs - ltot;
            #pragma unroll
            for (int j = 0; j < 5; j++) {
                int e = ebase + j;
                if (e < MAXT) {
                    float prod = after_lane + (suf[j] - sv[j]);
                    float sp = (e == t) ? dval
                                        : fmaxf(0.f, sv[j] - fmaxf(0.f, uval - prod));
                    float inner = fmaxf(0.f, 1.f - prod - sp);
                    sL[e] = sp;
                    aL[e] = fminf(sp, inner);
                }
            }
        }
        __syncthreads();
        {
            float racc = 0.f;
            for (int i2 = wv; i2 <= t; i2 += 4)
                racc += aL[i2] * bfbits2f(Vrow[(size_t)i2 * SDIM + lane]);
            red[wv][lane] = racc;
        }
        __syncthreads();
        if (wv == 0) {
            float rtv = red[0][lane] + red[1][lane] + red[2][lane] + red[3][lane];
            unsigned short hb = f2bfbits(rtv);
            unsigned short lb = f2bfbits(rtv - bfbits2f(hb));
            int d = lane, mt = brow >> 4, ksi2 = d >> 5, q = (d & 31) >> 3, e = d & 7;
            size_t fi = (((size_t)mt * 18 + ksi2) * 64 + q * 16 + (brow & 15)) * 8 + e;
            AfHn[fi] = hb;
            AfLn[fi] = lb;
        } else if (wv == 1 && t >= 129) {
            float a = outs[64 + lane];
            float bvv = outs[128 + lane];
            float m = fmaxf(a, bvv);
            #pragma unroll
            for (int off = 32; off; off >>= 1) m = fmaxf(m, __shfl_xor(m, off, 64));
            float e = expf(a - m) + expf(bvv - m);
            #pragma unroll
            for (int off = 32; off; off >>= 1) e += __shfl_xor(e, off, 64);
            float ls = logf(e) + m;
            size_t base = ((size_t)(t - 129) * BATCH + brow) * IDIM;
            if (isf32) {
                ((float*)dout)[base + lane] = a - ls;
                ((float*)dout)[base + lane + 64] = bvv - ls;
            } else {
                ((bf16*)dout)[base + lane] = __float2bfloat16(a - ls);
                ((bf16*)dout)[base + lane + 64] = __float2bfloat16(bvv - ls);
            }
        }
        grid_barrier(cnt, gen);
    }
}

extern "C" void kernel_launch(void* const* d_in, const int* in_sizes, int n_in,
                              void* d_out, int out_size, void* d_ws, size_t ws_size,
                              hipStream_t stream) {
    const void* x   = d_in[0];
    const void* Wih = d_in[1];
    const void* bih = d_in[2];
    const void* Whh = d_in[3];
    const void* bhh = d_in[4];
    const void* Wr  = d_in[5];
    const void* br  = d_in[6];

    char* base = (char*)d_ws;
    size_t off = 0;
    int* flag = (int*)base;                                   off += 64;
    unsigned* bar = (unsigned*)(base + off);                  off += 128;  // cnt @+0, gen @+64
    unsigned short* WfH  = (unsigned short*)(base + off);     off += (size_t)G4 * KTOT * 2;
    unsigned short* WfL  = (unsigned short*)(base + off);     off += (size_t)G4 * KTOT * 2;
    unsigned short* WrBh = (unsigned short*)(base + off);     off += (size_t)208 * HDIM * 2;
    unsigned short* WrBl = (unsigned short*)(base + off);     off += (size_t)208 * HDIM * 2;
    float* bc   = (float*)(base + off);                       off += G4 * 4;
    float* brf  = (float*)(base + off);                       off += 1024;
    unsigned short* xF = (unsigned short*)(base + off);       off += (size_t)130 * 16384 * 2;
    unsigned short* AfH = (unsigned short*)(base + off);      size_t afh_off = off;
                                                              off += (size_t)2 * AFRAG_SH * 2;
    unsigned short* AfL = (unsigned short*)(base + off);      off += (size_t)2 * AFRAG_SH * 2;
    float* hG = (float*)(base + off);                         off += (size_t)BATCH * HDIM * 4;
    unsigned short* Vb = (unsigned short*)(base + off);       off += (size_t)BATCH * MAXT * SDIM * 2;
    // total ~14.85 MB

    // zero barrier + both A-frag buffers each call (ws re-poisoned 0xAA by harness)
    hipMemsetAsync(base + 64, 0, 128, stream);
    hipMemsetAsync(base + afh_off, 0, (size_t)4 * AFRAG_SH * 2, stream);

    detect_kernel<<<1, 64, 0, stream>>>((const unsigned short*)Wih, flag);
    prep_kernel<<<G4, 256, 0, stream>>>(Wih, bih, Whh, bhh, WfH, WfL, bc, flag);
    wr_prep_kernel<<<208, 256, 0, stream>>>(Wr, br, WrBh, WrBl, brf, flag);
    x_prep_kernel<<<129, 256, 0, stream>>>(x, xF, flag);

    persist_kernel<<<NBLK, 256, 0, stream>>>(xF, WfH, WfL, bc, WrBh, WrBl, brf,
                                             AfH, AfL, hG, Vb, d_out, flag, bar);

    (void)in_sizes; (void)n_in; (void)out_size; (void)ws_size;
}